// Round 1
// baseline (144.122 us; speedup 1.0000x reference)
//
#include <hip/hip_runtime.h>
#include <hip/hip_bf16.h>
#include <stdint.h>

typedef unsigned short u16;
typedef __attribute__((ext_vector_type(2))) unsigned short u16x2;
typedef __attribute__((ext_vector_type(8))) unsigned short u16x8;
typedef __attribute__((ext_vector_type(8))) __bf16 bf16x8;
typedef __attribute__((ext_vector_type(4))) float f32x4;

__device__ __forceinline__ u16 f2bf(float f) {
    uint32_t u = __builtin_bit_cast(uint32_t, f);
    u = (u + 0x7fffu + ((u >> 16) & 1u)) >> 16;
    return (u16)u;
}

#define GLD_LDS16(src, dst) __builtin_amdgcn_global_load_lds( \
    (const __attribute__((address_space(1))) void*)(src),     \
    (__attribute__((address_space(3))) void*)(dst), 16, 0, 0)

// ---------------- Stage 1a: H12[r=i1*64+i2][a*8+b] = (G1[:,i1,:] @ G2[:,i2,:])[a][b]
__global__ __launch_bounds__(256) void h12_kernel(const float* __restrict__ f0,
                                                  const float* __restrict__ f1,
                                                  float* __restrict__ H12) {
    int gid = blockIdx.x * 256 + threadIdx.x;       // 0..262143
    int slice = gid >> 6;                            // i1*64+i2
    int e = gid & 63;
    int a = e >> 3, b = e & 7;
    int i1 = slice >> 6, i2 = slice & 63;
    float s = 0.f;
#pragma unroll
    for (int m = 0; m < 8; m++)
        s += f0[a * 512 + i1 * 8 + m] * f1[m * 512 + i2 * 8 + b];
    H12[gid] = s;
}

// ---------------- Stage 1b: H34mat[a*8+b][c=i3*16+i4] = (G3[:,i3,:] @ G4[:,i4,:])[b][a]
__global__ __launch_bounds__(256) void h34_kernel(const float* __restrict__ f2,
                                                  const float* __restrict__ f3,
                                                  float* __restrict__ H34) {
    int gid = blockIdx.x * 256 + threadIdx.x;       // 0..65535
    int slice = gid >> 6;                            // i3*16+i4
    int e = gid & 63;                                // e = d*8 + b  (k2 index = a*8+b with a=d)
    int d = e >> 3, b = e & 7;
    int i3 = slice >> 4, i4 = slice & 15;
    float s = 0.f;
#pragma unroll
    for (int c = 0; c < 8; c++)
        s += f2[b * 512 + i3 * 8 + c] * f3[c * 128 + i4 * 8 + d];
    H34[e * 1024 + slice] = s;
}

// ---------------- Stage 2: M2 = H12mat(4096x64) @ H34mat(64x1024), scatter into Wt[n][k] bf16
__global__ __launch_bounds__(256) void wgen_kernel(const float* __restrict__ H12,
                                                   const float* __restrict__ H34,
                                                   u16* __restrict__ Wt) {
    __shared__ float As[64][65];
    __shared__ float Bs[64][65];
    int c0 = blockIdx.x * 64;   // 0..15 -> cols of M2
    int r0 = blockIdx.y * 64;   // 0..63 -> rows of M2
    int tid = threadIdx.x;
    for (int idx = tid; idx < 4096; idx += 256) {
        int r = idx >> 6, k = idx & 63;
        As[r][k] = H12[(r0 + r) * 64 + k];
        Bs[r][k] = H34[r * 1024 + c0 + k];
    }
    __syncthreads();
    int rg = tid & 15;   // row group: rows r0 + rg*4 + i
    int cg = tid >> 4;   // col group: cols c0 + cg*4 + j
    float acc[4][4] = {};
    for (int k = 0; k < 64; k++) {
        float a[4], b[4];
#pragma unroll
        for (int i = 0; i < 4; i++) a[i] = As[rg * 4 + i][k];
#pragma unroll
        for (int j = 0; j < 4; j++) b[j] = Bs[k][cg * 4 + j];
#pragma unroll
        for (int i = 0; i < 4; i++)
#pragma unroll
            for (int j = 0; j < 4; j++) acc[i][j] += a[i] * b[j];
    }
    // r = r0 + rg*4 + i ; W row = r>>1, W col = (r&1)*1024 + c ; Wt[col][row]
    int Rb = (r0 >> 1) + rg * 2;
#pragma unroll
    for (int j = 0; j < 4; j++) {
        int c = c0 + cg * 4 + j;
        u16x2 lo, hi;
        lo[0] = f2bf(acc[0][j]); lo[1] = f2bf(acc[2][j]);   // parity 0 -> n=c
        hi[0] = f2bf(acc[1][j]); hi[1] = f2bf(acc[3][j]);   // parity 1 -> n=1024+c
        *(u16x2*)&Wt[(size_t)c * 2048 + Rb] = lo;
        *(u16x2*)&Wt[(size_t)(1024 + c) * 2048 + Rb] = hi;
    }
}

// ---------------- Stage 3: cast x (f32) -> bf16
__global__ __launch_bounds__(256) void xcast_kernel(const float* __restrict__ x,
                                                    u16* __restrict__ xb) {
    int i = (blockIdx.x * 256 + threadIdx.x) * 8;
    f32x4 a = *(const f32x4*)(x + i);
    f32x4 b = *(const f32x4*)(x + i + 4);
    u16x8 o;
    o[0] = f2bf(a[0]); o[1] = f2bf(a[1]); o[2] = f2bf(a[2]); o[3] = f2bf(a[3]);
    o[4] = f2bf(b[0]); o[5] = f2bf(b[1]); o[6] = f2bf(b[2]); o[7] = f2bf(b[3]);
    *(u16x8*)(xb + i) = o;
}

// ---------------- Stage 4: out(8192x2048 f32) = xb(8192x2048 bf16) @ Wt^T (Wt is [n][k])
__global__ __launch_bounds__(256) void gemm_kernel(const u16* __restrict__ A,
                                                   const u16* __restrict__ Bt,
                                                   float* __restrict__ C) {
    __shared__ u16 As[128][64];   // [m][k] 16 KB
    __shared__ u16 Bs[128][64];   // [n][k] 16 KB
    int bid = blockIdx.x;
    int wg = ((bid & 7) << 7) + (bid >> 3);   // XCD-aware bijective swizzle (1024 % 8 == 0)
    int bm = wg >> 4, bn = wg & 15;           // 64 x 16 block grid
    int m0 = bm << 7, n0 = bn << 7;
    int tid = threadIdx.x;
    int lane = tid & 63;
    int w = tid >> 6;                          // wave 0..3
    int wm = (w >> 1) * 64, wn = (w & 1) * 64; // wave's 64x64 sub-tile
    int lrow = lane >> 3;                      // staging: 8 rows per wave-issue
    int lcol = (lane & 7) << 3;                // staging: 8 bf16 (16B) per lane
    int lm = lane & 15;                        // fragment row/col
    int lk = (lane >> 4) << 3;                 // fragment k-offset (my bijective k-map)

    f32x4 acc[4][4] = {{{0.f}}};

    const u16* aBase = A + (size_t)(m0 + (w << 5) + lrow) * 2048 + lcol;
    const u16* bBase = Bt + (size_t)(n0 + (w << 5) + lrow) * 2048 + lcol;

#pragma unroll 1
    for (int kt = 0; kt < 2048; kt += 64) {
        __syncthreads();  // previous compute done before overwriting LDS
#pragma unroll
        for (int i = 0; i < 4; i++) {
            GLD_LDS16(aBase + kt + (size_t)(i * 8) * 2048, &As[(w << 5) + i * 8][0]);
            GLD_LDS16(bBase + kt + (size_t)(i * 8) * 2048, &Bs[(w << 5) + i * 8][0]);
        }
        __syncthreads();  // compiler drains vmcnt before barrier
#pragma unroll
        for (int kk = 0; kk < 64; kk += 32) {
            bf16x8 av[4], bv[4];
#pragma unroll
            for (int i = 0; i < 4; i++)
                av[i] = __builtin_bit_cast(bf16x8, *(const u16x8*)&As[wm + i * 16 + lm][kk + lk]);
#pragma unroll
            for (int j = 0; j < 4; j++)
                bv[j] = __builtin_bit_cast(bf16x8, *(const u16x8*)&Bs[wn + j * 16 + lm][kk + lk]);
#pragma unroll
            for (int i = 0; i < 4; i++)
#pragma unroll
                for (int j = 0; j < 4; j++)
                    acc[i][j] = __builtin_amdgcn_mfma_f32_16x16x32_bf16(av[i], bv[j], acc[i][j], 0, 0, 0);
        }
    }
    // C/D layout (measured m89/m91): col = lane&15, row = (lane>>4)*4 + reg
#pragma unroll
    for (int i = 0; i < 4; i++) {
        int row = m0 + wm + i * 16 + ((lane >> 4) << 2);
#pragma unroll
        for (int j = 0; j < 4; j++) {
            int col = n0 + wn + j * 16 + lm;
#pragma unroll
            for (int r = 0; r < 4; r++)
                C[(size_t)(row + r) * 2048 + col] = acc[i][j][r];
        }
    }
}

extern "C" void kernel_launch(void* const* d_in, const int* in_sizes, int n_in,
                              void* d_out, int out_size, void* d_ws, size_t ws_size,
                              hipStream_t stream) {
    const float* x  = (const float*)d_in[0];
    const float* f0 = (const float*)d_in[1];
    const float* f1 = (const float*)d_in[2];
    const float* f2 = (const float*)d_in[3];
    const float* f3 = (const float*)d_in[4];
    float* out = (float*)d_out;

    char* ws = (char*)d_ws;
    u16*   Wt  = (u16*)ws;                       // 8 MB  : W^T bf16 [2048][2048]
    float* H12 = (float*)(ws + (8u << 20));      // 1 MB  : [4096][64]
    float* H34 = (float*)(ws + (9u << 20));      // 256 KB: [64][1024]
    u16*   xb  = (u16*)(ws + (10u << 20));       // 32 MB : x in bf16
    if (ws_size < ((size_t)42 << 20)) return;    // fail loudly rather than corrupt

    h12_kernel<<<1024, 256, 0, stream>>>(f0, f1, H12);
    h34_kernel<<<256, 256, 0, stream>>>(f2, f3, H34);
    wgen_kernel<<<dim3(16, 64), 256, 0, stream>>>(H12, H34, Wt);
    xcast_kernel<<<8192, 256, 0, stream>>>(x, xb);
    gemm_kernel<<<1024, 256, 0, stream>>>(xb, Wt, out);
}

// Round 2
// 124.635 us; speedup vs baseline: 1.1563x; 1.1563x over previous
//
#include <hip/hip_runtime.h>
#include <hip/hip_bf16.h>
#include <stdint.h>

typedef unsigned short u16;
typedef __attribute__((ext_vector_type(2))) unsigned short u16x2;
typedef __attribute__((ext_vector_type(8))) unsigned short u16x8;
typedef __attribute__((ext_vector_type(8))) __bf16 bf16x8;
typedef __attribute__((ext_vector_type(4))) float f32x4;

__device__ __forceinline__ u16 f2bf(float f) {
    uint32_t u = __builtin_bit_cast(uint32_t, f);
    u = (u + 0x7fffu + ((u >> 16) & 1u)) >> 16;
    return (u16)u;
}

#define GLD_LDS16(src, dst) __builtin_amdgcn_global_load_lds( \
    (const __attribute__((address_space(1))) void*)(src),     \
    (__attribute__((address_space(3))) void*)(dst), 16, 0, 0)

// ---------------- Stage 1a: H12[r=i1*64+i2][a*8+b] = (G1[:,i1,:] @ G2[:,i2,:])[a][b]
__global__ __launch_bounds__(256) void h12_kernel(const float* __restrict__ f0,
                                                  const float* __restrict__ f1,
                                                  float* __restrict__ H12) {
    int gid = blockIdx.x * 256 + threadIdx.x;
    int slice = gid >> 6;
    int e = gid & 63;
    int a = e >> 3, b = e & 7;
    int i1 = slice >> 6, i2 = slice & 63;
    float s = 0.f;
#pragma unroll
    for (int m = 0; m < 8; m++)
        s += f0[a * 512 + i1 * 8 + m] * f1[m * 512 + i2 * 8 + b];
    H12[gid] = s;
}

// ---------------- Stage 1b: H34mat[a*8+b][c=i3*16+i4] = (G3[:,i3,:] @ G4[:,i4,:])[b][a]
__global__ __launch_bounds__(256) void h34_kernel(const float* __restrict__ f2,
                                                  const float* __restrict__ f3,
                                                  float* __restrict__ H34) {
    int gid = blockIdx.x * 256 + threadIdx.x;
    int slice = gid >> 6;
    int e = gid & 63;
    int d = e >> 3, b = e & 7;
    int i3 = slice >> 4, i4 = slice & 15;
    float s = 0.f;
#pragma unroll
    for (int c = 0; c < 8; c++)
        s += f2[b * 512 + i3 * 8 + c] * f3[c * 128 + i4 * 8 + d];
    H34[e * 1024 + slice] = s;
}

// ---------------- Stage 2: M2 = H12mat(4096x64) @ H34mat(64x1024), scatter into Wt[n][k] bf16
__global__ __launch_bounds__(256) void wgen_kernel(const float* __restrict__ H12,
                                                   const float* __restrict__ H34,
                                                   u16* __restrict__ Wt) {
    __shared__ float As_[64][65];
    __shared__ float Bs_[64][65];
    int c0 = blockIdx.x * 64;
    int r0 = blockIdx.y * 64;
    int tid = threadIdx.x;
    for (int idx = tid; idx < 4096; idx += 256) {
        int r = idx >> 6, k = idx & 63;
        As_[r][k] = H12[(r0 + r) * 64 + k];
        Bs_[r][k] = H34[r * 1024 + c0 + k];
    }
    __syncthreads();
    int rg = tid & 15;
    int cg = tid >> 4;
    float acc[4][4] = {};
    for (int k = 0; k < 64; k++) {
        float a[4], b[4];
#pragma unroll
        for (int i = 0; i < 4; i++) a[i] = As_[rg * 4 + i][k];
#pragma unroll
        for (int j = 0; j < 4; j++) b[j] = Bs_[k][cg * 4 + j];
#pragma unroll
        for (int i = 0; i < 4; i++)
#pragma unroll
            for (int j = 0; j < 4; j++) acc[i][j] += a[i] * b[j];
    }
    int Rb = (r0 >> 1) + rg * 2;
#pragma unroll
    for (int j = 0; j < 4; j++) {
        int c = c0 + cg * 4 + j;
        u16x2 lo, hi;
        lo[0] = f2bf(acc[0][j]); lo[1] = f2bf(acc[2][j]);
        hi[0] = f2bf(acc[1][j]); hi[1] = f2bf(acc[3][j]);
        *(u16x2*)&Wt[(size_t)c * 2048 + Rb] = lo;
        *(u16x2*)&Wt[(size_t)(1024 + c) * 2048 + Rb] = hi;
    }
}

// ---------------- Stage 3: cast x (f32) -> bf16
__global__ __launch_bounds__(256) void xcast_kernel(const float* __restrict__ x,
                                                    u16* __restrict__ xb) {
    int i = (blockIdx.x * 256 + threadIdx.x) * 8;
    f32x4 a = *(const f32x4*)(x + i);
    f32x4 b = *(const f32x4*)(x + i + 4);
    u16x8 o;
    o[0] = f2bf(a[0]); o[1] = f2bf(a[1]); o[2] = f2bf(a[2]); o[3] = f2bf(a[3]);
    o[4] = f2bf(b[0]); o[5] = f2bf(b[1]); o[6] = f2bf(b[2]); o[7] = f2bf(b[3]);
    *(u16x8*)(xb + i) = o;
}

// ---------------- Stage 4: 256x256 tile, BK=64, 8 waves, 8-phase schedule
template<int M0, int M1>
__device__ __forceinline__ void phase_mfma(f32x4 (&acc)[8][4], const bf16x8 (&bv)[4][2],
                                           const bf16x8 (&a0)[2], const bf16x8 (&a1)[2]) {
    __builtin_amdgcn_s_setprio(1);
#pragma unroll
    for (int j = 0; j < 4; ++j) {
        acc[M0][j] = __builtin_amdgcn_mfma_f32_16x16x32_bf16(a0[0], bv[j][0], acc[M0][j], 0, 0, 0);
        acc[M1][j] = __builtin_amdgcn_mfma_f32_16x16x32_bf16(a1[0], bv[j][0], acc[M1][j], 0, 0, 0);
        acc[M0][j] = __builtin_amdgcn_mfma_f32_16x16x32_bf16(a0[1], bv[j][1], acc[M0][j], 0, 0, 0);
        acc[M1][j] = __builtin_amdgcn_mfma_f32_16x16x32_bf16(a1[1], bv[j][1], acc[M1][j], 0, 0, 0);
    }
    __builtin_amdgcn_s_setprio(0);
}

__global__ __launch_bounds__(512, 2) void gemm_kernel(const u16* __restrict__ A,
                                                      const u16* __restrict__ Bt,
                                                      float* __restrict__ C) {
    __shared__ u16 As[2][256][64];   // 64 KB
    __shared__ u16 Bs[2][256][64];   // 64 KB
    constexpr int NT = 2048 / 64;    // 32 K-tiles

    int bid = blockIdx.x;
    int wg = ((bid & 7) << 5) | (bid >> 3);   // XCD swizzle, 256 % 8 == 0 -> bijective
    int bm = wg >> 3, bn = wg & 7;
    int m0 = bm << 8, n0 = bn << 8;

    int tid = threadIdx.x;
    int lane = tid & 63;
    int w = tid >> 6;        // 0..7
    int wM = w >> 2;         // 0..1 -> M offset wM*128
    int wN = w & 3;          // 0..3 -> N offset wN*64
    int lm = lane & 15;
    int lkE = (lane >> 4) << 3;        // k element offset 0/8/16/24
    int swzR = (lm & 7) << 3;          // read-side XOR (elements)

    // staging: thread tid covers row (tid>>3) of a 64-row issue region,
    // source column pre-inverse-swizzled so linear LDS + swizzled read match
    int srow = tid >> 3;
    int scol = ((tid & 7) ^ (srow & 7)) << 3;
    const u16* aSrc = A + (size_t)(m0 + srow) * 2048 + scol;
    const u16* bSrc = Bt + (size_t)(n0 + srow) * 2048 + scol;

#define ISSUE_A(sl, tt, q) GLD_LDS16(aSrc + (size_t)(q) * 64 * 2048 + (size_t)(tt) * 64, \
                                     &As[sl][(q) * 64 + (w << 3)][0])
#define ISSUE_B(sl, tt, q) GLD_LDS16(bSrc + (size_t)(q) * 64 * 2048 + (size_t)(tt) * 64, \
                                     &Bs[sl][(q) * 64 + (w << 3)][0])
#define LOAD_AF(dst, mf) do { \
    dst[0] = __builtin_bit_cast(bf16x8, *(const u16x8*)(aT + (mf) * 1024 + (lkE ^ swzR))); \
    dst[1] = __builtin_bit_cast(bf16x8, *(const u16x8*)(aT + (mf) * 1024 + ((32 + lkE) ^ swzR))); \
} while (0)
#define LOAD_BF(dst, nf) do { \
    dst[0] = __builtin_bit_cast(bf16x8, *(const u16x8*)(bT + (nf) * 1024 + (lkE ^ swzR))); \
    dst[1] = __builtin_bit_cast(bf16x8, *(const u16x8*)(bT + (nf) * 1024 + ((32 + lkE) ^ swzR))); \
} while (0)

    f32x4 acc[8][4];
#pragma unroll
    for (int i = 0; i < 8; ++i)
#pragma unroll
        for (int j = 0; j < 4; ++j) acc[i][j] = (f32x4){0.f, 0.f, 0.f, 0.f};

    // prologue: A(0), B(0), then B(1); allow B(1) to stay in flight
    ISSUE_A(0, 0, 0); ISSUE_A(0, 0, 1); ISSUE_A(0, 0, 2); ISSUE_A(0, 0, 3);
    ISSUE_B(0, 0, 0); ISSUE_B(0, 0, 1); ISSUE_B(0, 0, 2); ISSUE_B(0, 0, 3);
    ISSUE_B(1, 1, 0); ISSUE_B(1, 1, 1); ISSUE_B(1, 1, 2); ISSUE_B(1, 1, 3);
    asm volatile("s_waitcnt vmcnt(4)" ::: "memory");
    __builtin_amdgcn_s_barrier();

    const u16* aF = &As[0][0][0] + (wM * 128 + lm) * 64;
    const u16* bF = &Bs[0][0][0] + (wN * 64 + lm) * 64;

#pragma unroll 1
    for (int t = 0; t < NT; ++t) {
        const int slot = t & 1;
        const u16* aT = aF + slot * 16384;
        const u16* bT = bF + slot * 16384;
        bf16x8 bv[4][2], fA[2][2], fB[2][2];

        // ---- phase 0: stage A(t+1) h0; frags B all + A mf0,1 ----
        if (t + 1 < NT) { ISSUE_A(slot ^ 1, t + 1, 0); ISSUE_A(slot ^ 1, t + 1, 1); }
        LOAD_BF(bv[0], 0); LOAD_BF(bv[1], 1); LOAD_BF(bv[2], 2); LOAD_BF(bv[3], 3);
        LOAD_AF(fA[0], 0); LOAD_AF(fA[1], 1);
        __builtin_amdgcn_s_barrier();
        asm volatile("s_waitcnt lgkmcnt(0)" ::: "memory");
        phase_mfma<0, 1>(acc, bv, fA[0], fA[1]);
        __builtin_amdgcn_s_barrier();

        // ---- phase 1: stage A(t+1) h1; frags A mf2,3 ----
        if (t + 1 < NT) { ISSUE_A(slot ^ 1, t + 1, 2); ISSUE_A(slot ^ 1, t + 1, 3); }
        LOAD_AF(fB[0], 2); LOAD_AF(fB[1], 3);
        __builtin_amdgcn_s_barrier();
        asm volatile("s_waitcnt lgkmcnt(0)" ::: "memory");
        phase_mfma<2, 3>(acc, bv, fB[0], fB[1]);
        __builtin_amdgcn_s_barrier();

        // ---- phase 2: stage B(t+2) h0 into B-slot freed after phase 0 ----
        if (t + 2 < NT) { ISSUE_B(slot, t + 2, 0); ISSUE_B(slot, t + 2, 1); }
        LOAD_AF(fA[0], 4); LOAD_AF(fA[1], 5);
        __builtin_amdgcn_s_barrier();
        asm volatile("s_waitcnt lgkmcnt(0)" ::: "memory");
        phase_mfma<4, 5>(acc, bv, fA[0], fA[1]);
        __builtin_amdgcn_s_barrier();

        // ---- phase 3: stage B(t+2) h1; boundary counted-vmcnt ----
        if (t + 2 < NT) { ISSUE_B(slot, t + 2, 2); ISSUE_B(slot, t + 2, 3); }
        LOAD_AF(fB[0], 6); LOAD_AF(fB[1], 7);
        __builtin_amdgcn_s_barrier();
        asm volatile("s_waitcnt lgkmcnt(0)" ::: "memory");
        phase_mfma<6, 7>(acc, bv, fB[0], fB[1]);
        if (t < NT - 2) {
            asm volatile("s_waitcnt vmcnt(4)" ::: "memory");   // keep B(t+2) in flight
            __builtin_amdgcn_s_barrier();
        } else if (t == NT - 2) {
            asm volatile("s_waitcnt vmcnt(0)" ::: "memory");   // drain last A
            __builtin_amdgcn_s_barrier();
        }
    }

    // epilogue: C/D layout col=lane&15, row=(lane>>4)*4+r (verified round 1)
    float* cW = C + (size_t)(m0 + wM * 128 + ((lane >> 4) << 2)) * 2048 + (n0 + wN * 64 + lm);
#pragma unroll
    for (int i = 0; i < 8; ++i)
#pragma unroll
        for (int j = 0; j < 4; ++j) {
            f32x4 v = acc[i][j];
#pragma unroll
            for (int r = 0; r < 4; ++r)
                cW[(size_t)(i * 16 + r) * 2048 + j * 16] = v[r];
        }
}

extern "C" void kernel_launch(void* const* d_in, const int* in_sizes, int n_in,
                              void* d_out, int out_size, void* d_ws, size_t ws_size,
                              hipStream_t stream) {
    const float* x  = (const float*)d_in[0];
    const float* f0 = (const float*)d_in[1];
    const float* f1 = (const float*)d_in[2];
    const float* f2 = (const float*)d_in[3];
    const float* f3 = (const float*)d_in[4];
    float* out = (float*)d_out;

    char* ws = (char*)d_ws;
    u16*   Wt  = (u16*)ws;                       // 8 MB  : W^T bf16 [2048][2048]
    float* H12 = (float*)(ws + (8u << 20));      // 1 MB  : [4096][64]
    float* H34 = (float*)(ws + (9u << 20));      // 256 KB: [64][1024]
    u16*   xb  = (u16*)(ws + (10u << 20));       // 32 MB : x in bf16
    if (ws_size < ((size_t)42 << 20)) return;

    h12_kernel<<<1024, 256, 0, stream>>>(f0, f1, H12);
    h34_kernel<<<256, 256, 0, stream>>>(f2, f3, H34);
    wgen_kernel<<<dim3(16, 64), 256, 0, stream>>>(H12, H34, Wt);
    xcast_kernel<<<8192, 256, 0, stream>>>(x, xb);
    gemm_kernel<<<256, 512, 0, stream>>>(xb, Wt, out);
}

// Round 3
// 124.364 us; speedup vs baseline: 1.1589x; 1.0022x over previous
//
#include <hip/hip_runtime.h>
#include <hip/hip_bf16.h>
#include <stdint.h>

typedef unsigned short u16;
typedef __attribute__((ext_vector_type(2))) unsigned short u16x2;
typedef __attribute__((ext_vector_type(8))) unsigned short u16x8;
typedef __attribute__((ext_vector_type(8))) __bf16 bf16x8;
typedef __attribute__((ext_vector_type(4))) float f32x4;

__device__ __forceinline__ u16 f2bf(float f) {
    uint32_t u = __builtin_bit_cast(uint32_t, f);
    u = (u + 0x7fffu + ((u >> 16) & 1u)) >> 16;
    return (u16)u;
}

#define GLD_LDS16(src, dst) __builtin_amdgcn_global_load_lds( \
    (const __attribute__((address_space(1))) void*)(src),     \
    (__attribute__((address_space(3))) void*)(dst), 16, 0, 0)

// ---------------- Stage 1a: H12[r=i1*64+i2][a*8+b] = (G1[:,i1,:] @ G2[:,i2,:])[a][b]
__global__ __launch_bounds__(256) void h12_kernel(const float* __restrict__ f0,
                                                  const float* __restrict__ f1,
                                                  float* __restrict__ H12) {
    int gid = blockIdx.x * 256 + threadIdx.x;
    int slice = gid >> 6;
    int e = gid & 63;
    int a = e >> 3, b = e & 7;
    int i1 = slice >> 6, i2 = slice & 63;
    float s = 0.f;
#pragma unroll
    for (int m = 0; m < 8; m++)
        s += f0[a * 512 + i1 * 8 + m] * f1[m * 512 + i2 * 8 + b];
    H12[gid] = s;
}

// ---------------- Stage 1b: H34mat[a*8+b][c=i3*16+i4] = (G3[:,i3,:] @ G4[:,i4,:])[b][a]
__global__ __launch_bounds__(256) void h34_kernel(const float* __restrict__ f2,
                                                  const float* __restrict__ f3,
                                                  float* __restrict__ H34) {
    int gid = blockIdx.x * 256 + threadIdx.x;
    int slice = gid >> 6;
    int e = gid & 63;
    int d = e >> 3, b = e & 7;
    int i3 = slice >> 4, i4 = slice & 15;
    float s = 0.f;
#pragma unroll
    for (int c = 0; c < 8; c++)
        s += f2[b * 512 + i3 * 8 + c] * f3[c * 128 + i4 * 8 + d];
    H34[e * 1024 + slice] = s;
}

// ---------------- Stage 2: M2 = H12mat(4096x64) @ H34mat(64x1024), scatter into Wt[n][k] bf16
__global__ __launch_bounds__(256) void wgen_kernel(const float* __restrict__ H12,
                                                   const float* __restrict__ H34,
                                                   u16* __restrict__ Wt) {
    __shared__ float As_[64][65];
    __shared__ float Bs_[64][65];
    int c0 = blockIdx.x * 64;
    int r0 = blockIdx.y * 64;
    int tid = threadIdx.x;
    for (int idx = tid; idx < 4096; idx += 256) {
        int r = idx >> 6, k = idx & 63;
        As_[r][k] = H12[(r0 + r) * 64 + k];
        Bs_[r][k] = H34[r * 1024 + c0 + k];
    }
    __syncthreads();
    int rg = tid & 15;
    int cg = tid >> 4;
    float acc[4][4] = {};
    for (int k = 0; k < 64; k++) {
        float a[4], b[4];
#pragma unroll
        for (int i = 0; i < 4; i++) a[i] = As_[rg * 4 + i][k];
#pragma unroll
        for (int j = 0; j < 4; j++) b[j] = Bs_[k][cg * 4 + j];
#pragma unroll
        for (int i = 0; i < 4; i++)
#pragma unroll
            for (int j = 0; j < 4; j++) acc[i][j] += a[i] * b[j];
    }
    int Rb = (r0 >> 1) + rg * 2;
#pragma unroll
    for (int j = 0; j < 4; j++) {
        int c = c0 + cg * 4 + j;
        u16x2 lo, hi;
        lo[0] = f2bf(acc[0][j]); lo[1] = f2bf(acc[2][j]);
        hi[0] = f2bf(acc[1][j]); hi[1] = f2bf(acc[3][j]);
        *(u16x2*)&Wt[(size_t)c * 2048 + Rb] = lo;
        *(u16x2*)&Wt[(size_t)(1024 + c) * 2048 + Rb] = hi;
    }
}

// ---------------- Stage 3: cast x (f32) -> bf16
__global__ __launch_bounds__(256) void xcast_kernel(const float* __restrict__ x,
                                                    u16* __restrict__ xb) {
    int i = (blockIdx.x * 256 + threadIdx.x) * 8;
    f32x4 a = *(const f32x4*)(x + i);
    f32x4 b = *(const f32x4*)(x + i + 4);
    u16x8 o;
    o[0] = f2bf(a[0]); o[1] = f2bf(a[1]); o[2] = f2bf(a[2]); o[3] = f2bf(a[3]);
    o[4] = f2bf(b[0]); o[5] = f2bf(b[1]); o[6] = f2bf(b[2]); o[7] = f2bf(b[3]);
    *(u16x8*)(xb + i) = o;
}

// ---------------- Stage 4: 256x256 tile, BK=64, 8 waves, 8-phase schedule
// MFMA burst reordered: all 8 k0-slice MFMAs, then all 8 k1-slice MFMAs
// (dep distance 2 -> 8, so convoyed waves don't stall the matrix pipe).
template<int M0, int M1>
__device__ __forceinline__ void phase_mfma(f32x4 (&acc)[8][4], const bf16x8 (&bv)[4][2],
                                           const bf16x8 (&a0)[2], const bf16x8 (&a1)[2]) {
    __builtin_amdgcn_s_setprio(1);
#pragma unroll
    for (int j = 0; j < 4; ++j) {
        acc[M0][j] = __builtin_amdgcn_mfma_f32_16x16x32_bf16(a0[0], bv[j][0], acc[M0][j], 0, 0, 0);
        acc[M1][j] = __builtin_amdgcn_mfma_f32_16x16x32_bf16(a1[0], bv[j][0], acc[M1][j], 0, 0, 0);
    }
#pragma unroll
    for (int j = 0; j < 4; ++j) {
        acc[M0][j] = __builtin_amdgcn_mfma_f32_16x16x32_bf16(a0[1], bv[j][1], acc[M0][j], 0, 0, 0);
        acc[M1][j] = __builtin_amdgcn_mfma_f32_16x16x32_bf16(a1[1], bv[j][1], acc[M1][j], 0, 0, 0);
    }
    __builtin_amdgcn_s_setprio(0);
}

__global__ __launch_bounds__(512, 2) void gemm_kernel(const u16* __restrict__ A,
                                                      const u16* __restrict__ Bt,
                                                      float* __restrict__ C) {
    __shared__ u16 As[2][256][64];   // 64 KB
    __shared__ u16 Bs[2][256][64];   // 64 KB
    constexpr int NT = 2048 / 64;    // 32 K-tiles

    int bid = blockIdx.x;
    int wg = ((bid & 7) << 5) | (bid >> 3);   // XCD swizzle, 256 % 8 == 0 -> bijective
    int bm = wg >> 3, bn = wg & 7;
    int m0 = bm << 8, n0 = bn << 8;

    int tid = threadIdx.x;
    int lane = tid & 63;
    int w = tid >> 6;        // 0..7
    int wM = w >> 2;         // 0..1 -> M offset wM*128
    int wN = w & 3;          // 0..3 -> N offset wN*64
    int lm = lane & 15;
    int lkE = (lane >> 4) << 3;        // k element offset 0/8/16/24
    int swzR = (lm & 7) << 3;          // read-side XOR (elements)

    int srow = tid >> 3;
    int scol = ((tid & 7) ^ (srow & 7)) << 3;
    const u16* aSrc = A + (size_t)(m0 + srow) * 2048 + scol;
    const u16* bSrc = Bt + (size_t)(n0 + srow) * 2048 + scol;

#define ISSUE_A(sl, tt, q) GLD_LDS16(aSrc + (size_t)(q) * 64 * 2048 + (size_t)(tt) * 64, \
                                     &As[sl][(q) * 64 + (w << 3)][0])
#define ISSUE_B(sl, tt, q) GLD_LDS16(bSrc + (size_t)(q) * 64 * 2048 + (size_t)(tt) * 64, \
                                     &Bs[sl][(q) * 64 + (w << 3)][0])
#define LOAD_AF(dst, mf) do { \
    dst[0] = __builtin_bit_cast(bf16x8, *(const u16x8*)(aT + (mf) * 1024 + (lkE ^ swzR))); \
    dst[1] = __builtin_bit_cast(bf16x8, *(const u16x8*)(aT + (mf) * 1024 + ((32 + lkE) ^ swzR))); \
} while (0)
#define LOAD_BF(dst, nf) do { \
    dst[0] = __builtin_bit_cast(bf16x8, *(const u16x8*)(bT + (nf) * 1024 + (lkE ^ swzR))); \
    dst[1] = __builtin_bit_cast(bf16x8, *(const u16x8*)(bT + (nf) * 1024 + ((32 + lkE) ^ swzR))); \
} while (0)
#define WAIT_LGKM0_PIN() do { \
    asm volatile("s_waitcnt lgkmcnt(0)" ::: "memory"); \
    __builtin_amdgcn_sched_barrier(0); \
} while (0)

    f32x4 acc[8][4];
#pragma unroll
    for (int i = 0; i < 8; ++i)
#pragma unroll
        for (int j = 0; j < 4; ++j) acc[i][j] = (f32x4){0.f, 0.f, 0.f, 0.f};

    // prologue: A(0), B(0), then B(1); allow B(1) to stay in flight
    ISSUE_A(0, 0, 0); ISSUE_A(0, 0, 1); ISSUE_A(0, 0, 2); ISSUE_A(0, 0, 3);
    ISSUE_B(0, 0, 0); ISSUE_B(0, 0, 1); ISSUE_B(0, 0, 2); ISSUE_B(0, 0, 3);
    ISSUE_B(1, 1, 0); ISSUE_B(1, 1, 1); ISSUE_B(1, 1, 2); ISSUE_B(1, 1, 3);
    asm volatile("s_waitcnt vmcnt(4)" ::: "memory");
    __builtin_amdgcn_s_barrier();

    const u16* aF = &As[0][0][0] + (wM * 128 + lm) * 64;
    const u16* bF = &Bs[0][0][0] + (wN * 64 + lm) * 64;

#pragma unroll 1
    for (int t = 0; t < NT; ++t) {
        const int slot = t & 1;
        const u16* aT = aF + slot * 16384;
        const u16* bT = bF + slot * 16384;
        bf16x8 bv[4][2], fA[2][2], fB[2][2];

        // ---- phase 0: stage A(t+1) h0; frags B all + A mf0,1 (12 ds_reads) ----
        if (t + 1 < NT) { ISSUE_A(slot ^ 1, t + 1, 0); ISSUE_A(slot ^ 1, t + 1, 1); }
        LOAD_BF(bv[0], 0); LOAD_BF(bv[1], 1); LOAD_BF(bv[2], 2); LOAD_BF(bv[3], 3);
        LOAD_AF(fA[0], 0); LOAD_AF(fA[1], 1);
        asm volatile("s_waitcnt lgkmcnt(8)" ::: "memory");   // don't carry 12 into barrier
        __builtin_amdgcn_s_barrier();
        WAIT_LGKM0_PIN();
        phase_mfma<0, 1>(acc, bv, fA[0], fA[1]);
        __builtin_amdgcn_s_barrier();

        // ---- phase 1: stage A(t+1) h1; frags A mf2,3 ----
        if (t + 1 < NT) { ISSUE_A(slot ^ 1, t + 1, 2); ISSUE_A(slot ^ 1, t + 1, 3); }
        LOAD_AF(fB[0], 2); LOAD_AF(fB[1], 3);
        __builtin_amdgcn_s_barrier();
        WAIT_LGKM0_PIN();
        phase_mfma<2, 3>(acc, bv, fB[0], fB[1]);
        __builtin_amdgcn_s_barrier();

        // ---- phase 2: stage B(t+2) h0 into B-slot freed after phase 0 ----
        if (t + 2 < NT) { ISSUE_B(slot, t + 2, 0); ISSUE_B(slot, t + 2, 1); }
        LOAD_AF(fA[0], 4); LOAD_AF(fA[1], 5);
        __builtin_amdgcn_s_barrier();
        WAIT_LGKM0_PIN();
        phase_mfma<4, 5>(acc, bv, fA[0], fA[1]);
        __builtin_amdgcn_s_barrier();

        // ---- phase 3: stage B(t+2) h1; boundary counted-vmcnt ----
        if (t + 2 < NT) { ISSUE_B(slot, t + 2, 2); ISSUE_B(slot, t + 2, 3); }
        LOAD_AF(fB[0], 6); LOAD_AF(fB[1], 7);
        __builtin_amdgcn_s_barrier();
        WAIT_LGKM0_PIN();
        phase_mfma<6, 7>(acc, bv, fB[0], fB[1]);
        if (t < NT - 2) {
            asm volatile("s_waitcnt vmcnt(4)" ::: "memory");   // keep B(t+2) in flight
            __builtin_amdgcn_s_barrier();
        } else if (t == NT - 2) {
            asm volatile("s_waitcnt vmcnt(0)" ::: "memory");   // drain last A+B
            __builtin_amdgcn_s_barrier();
        }
    }

    // epilogue: C/D layout col=lane&15, row=(lane>>4)*4+r (verified round 1)
    float* cW = C + (size_t)(m0 + wM * 128 + ((lane >> 4) << 2)) * 2048 + (n0 + wN * 64 + lm);
#pragma unroll
    for (int i = 0; i < 8; ++i)
#pragma unroll
        for (int j = 0; j < 4; ++j) {
            f32x4 v = acc[i][j];
#pragma unroll
            for (int r = 0; r < 4; ++r)
                cW[(size_t)(i * 16 + r) * 2048 + j * 16] = v[r];
        }
}

extern "C" void kernel_launch(void* const* d_in, const int* in_sizes, int n_in,
                              void* d_out, int out_size, void* d_ws, size_t ws_size,
                              hipStream_t stream) {
    const float* x  = (const float*)d_in[0];
    const float* f0 = (const float*)d_in[1];
    const float* f1 = (const float*)d_in[2];
    const float* f2 = (const float*)d_in[3];
    const float* f3 = (const float*)d_in[4];
    float* out = (float*)d_out;

    char* ws = (char*)d_ws;
    u16*   Wt  = (u16*)ws;                       // 8 MB  : W^T bf16 [2048][2048]
    float* H12 = (float*)(ws + (8u << 20));      // 1 MB  : [4096][64]
    float* H34 = (float*)(ws + (9u << 20));      // 256 KB: [64][1024]
    u16*   xb  = (u16*)(ws + (10u << 20));       // 32 MB : x in bf16
    if (ws_size < ((size_t)42 << 20)) return;

    h12_kernel<<<1024, 256, 0, stream>>>(f0, f1, H12);
    h34_kernel<<<256, 256, 0, stream>>>(f2, f3, H34);
    wgen_kernel<<<dim3(16, 64), 256, 0, stream>>>(H12, H34, Wt);
    xcast_kernel<<<8192, 256, 0, stream>>>(x, xb);
    gemm_kernel<<<256, 512, 0, stream>>>(xb, Wt, out);
}

// Round 4
// 117.206 us; speedup vs baseline: 1.2296x; 1.0611x over previous
//
#include <hip/hip_runtime.h>
#include <hip/hip_bf16.h>
#include <stdint.h>

typedef unsigned short u16;
typedef __attribute__((ext_vector_type(2))) unsigned short u16x2;
typedef __attribute__((ext_vector_type(8))) unsigned short u16x8;
typedef __attribute__((ext_vector_type(8))) __bf16 bf16x8;
typedef __attribute__((ext_vector_type(4))) float f32x4;

__device__ __forceinline__ u16 f2bf(float f) {
    uint32_t u = __builtin_bit_cast(uint32_t, f);
    u = (u + 0x7fffu + ((u >> 16) & 1u)) >> 16;
    return (u16)u;
}

#define GLD_LDS16(src, dst) __builtin_amdgcn_global_load_lds( \
    (const __attribute__((address_space(1))) void*)(src),     \
    (__attribute__((address_space(3))) void*)(dst), 16, 0, 0)

// ---------------- Stage 1a: H12[r=i1*64+i2][a*8+b] = (G1[:,i1,:] @ G2[:,i2,:])[a][b]
__global__ __launch_bounds__(256) void h12_kernel(const float* __restrict__ f0,
                                                  const float* __restrict__ f1,
                                                  float* __restrict__ H12) {
    int gid = blockIdx.x * 256 + threadIdx.x;
    int slice = gid >> 6;
    int e = gid & 63;
    int a = e >> 3, b = e & 7;
    int i1 = slice >> 6, i2 = slice & 63;
    float s = 0.f;
#pragma unroll
    for (int m = 0; m < 8; m++)
        s += f0[a * 512 + i1 * 8 + m] * f1[m * 512 + i2 * 8 + b];
    H12[gid] = s;
}

// ---------------- Stage 1b: H34mat[a*8+b][c=i3*16+i4] = (G3[:,i3,:] @ G4[:,i4,:])[b][a]
__global__ __launch_bounds__(256) void h34_kernel(const float* __restrict__ f2,
                                                  const float* __restrict__ f3,
                                                  float* __restrict__ H34) {
    int gid = blockIdx.x * 256 + threadIdx.x;
    int slice = gid >> 6;
    int e = gid & 63;
    int d = e >> 3, b = e & 7;
    int i3 = slice >> 4, i4 = slice & 15;
    float s = 0.f;
#pragma unroll
    for (int c = 0; c < 8; c++)
        s += f2[b * 512 + i3 * 8 + c] * f3[c * 128 + i4 * 8 + d];
    H34[e * 1024 + slice] = s;
}

// ---------------- Stage 2: M2 = H12mat(4096x64) @ H34mat(64x1024), scatter into Wt[n][k] bf16
__global__ __launch_bounds__(256) void wgen_kernel(const float* __restrict__ H12,
                                                   const float* __restrict__ H34,
                                                   u16* __restrict__ Wt) {
    __shared__ float As_[64][65];
    __shared__ float Bs_[64][65];
    int c0 = blockIdx.x * 64;
    int r0 = blockIdx.y * 64;
    int tid = threadIdx.x;
    for (int idx = tid; idx < 4096; idx += 256) {
        int r = idx >> 6, k = idx & 63;
        As_[r][k] = H12[(r0 + r) * 64 + k];
        Bs_[r][k] = H34[r * 1024 + c0 + k];
    }
    __syncthreads();
    int rg = tid & 15;
    int cg = tid >> 4;
    float acc[4][4] = {};
    for (int k = 0; k < 64; k++) {
        float a[4], b[4];
#pragma unroll
        for (int i = 0; i < 4; i++) a[i] = As_[rg * 4 + i][k];
#pragma unroll
        for (int j = 0; j < 4; j++) b[j] = Bs_[k][cg * 4 + j];
#pragma unroll
        for (int i = 0; i < 4; i++)
#pragma unroll
            for (int j = 0; j < 4; j++) acc[i][j] += a[i] * b[j];
    }
    int Rb = (r0 >> 1) + rg * 2;
#pragma unroll
    for (int j = 0; j < 4; j++) {
        int c = c0 + cg * 4 + j;
        u16x2 lo, hi;
        lo[0] = f2bf(acc[0][j]); lo[1] = f2bf(acc[2][j]);
        hi[0] = f2bf(acc[1][j]); hi[1] = f2bf(acc[3][j]);
        *(u16x2*)&Wt[(size_t)c * 2048 + Rb] = lo;
        *(u16x2*)&Wt[(size_t)(1024 + c) * 2048 + Rb] = hi;
    }
}

// ---------------- Stage 3: cast x (f32) -> bf16
__global__ __launch_bounds__(256) void xcast_kernel(const float* __restrict__ x,
                                                    u16* __restrict__ xb) {
    int i = (blockIdx.x * 256 + threadIdx.x) * 8;
    f32x4 a = *(const f32x4*)(x + i);
    f32x4 b = *(const f32x4*)(x + i + 4);
    u16x8 o;
    o[0] = f2bf(a[0]); o[1] = f2bf(a[1]); o[2] = f2bf(a[2]); o[3] = f2bf(a[3]);
    o[4] = f2bf(b[0]); o[5] = f2bf(b[1]); o[6] = f2bf(b[2]); o[7] = f2bf(b[3]);
    *(u16x8*)(xb + i) = o;
}

// ---------------- Stage 4: 256x256 tile, BK=64, 8 waves, 2 phases/K-tile
// Phase = one k-half (K=32): 32 MFMA burst. 4 barriers/tile (was 8).
// No explicit lgkmcnt / sched_barrier: ds_reads are compiler-visible, so the
// compiler emits fine-grained lgkmcnt(N) letting early MFMAs overlap late reads.
__global__ __launch_bounds__(512, 2) void gemm_kernel(const u16* __restrict__ A,
                                                      const u16* __restrict__ Bt,
                                                      float* __restrict__ C) {
    __shared__ u16 As[2][256][64];   // 64 KB
    __shared__ u16 Bs[2][256][64];   // 64 KB
    constexpr int NT = 2048 / 64;    // 32 K-tiles

    int bid = blockIdx.x;
    int wg = ((bid & 7) << 5) | (bid >> 3);   // XCD swizzle, 256 % 8 == 0 -> bijective
    int bm = wg >> 3, bn = wg & 7;
    int m0 = bm << 8, n0 = bn << 8;

    int tid = threadIdx.x;
    int lane = tid & 63;
    int w = tid >> 6;        // 0..7
    int wM = w >> 2;         // 0..1 -> M offset wM*128
    int wN = w & 3;          // 0..3 -> N offset wN*64
    int lm = lane & 15;
    int lkE = (lane >> 4) << 3;        // k element offset 0/8/16/24
    int swzR = (lm & 7) << 3;          // read-side XOR (elements)

    int srow = tid >> 3;
    int scol = ((tid & 7) ^ (srow & 7)) << 3;
    const u16* aSrc = A + (size_t)(m0 + srow) * 2048 + scol;
    const u16* bSrc = Bt + (size_t)(n0 + srow) * 2048 + scol;

#define ISSUE_A(sl, tt, q) GLD_LDS16(aSrc + (size_t)(q) * 64 * 2048 + (size_t)(tt) * 64, \
                                     &As[sl][(q) * 64 + (w << 3)][0])
#define ISSUE_B(sl, tt, q) GLD_LDS16(bSrc + (size_t)(q) * 64 * 2048 + (size_t)(tt) * 64, \
                                     &Bs[sl][(q) * 64 + (w << 3)][0])
#define LDAH(mf, h) __builtin_bit_cast(bf16x8, *(const u16x8*)(aT + (mf) * 1024 + (((h) * 32 + lkE) ^ swzR)))
#define LDBH(nf, h) __builtin_bit_cast(bf16x8, *(const u16x8*)(bT + (nf) * 1024 + (((h) * 32 + lkE) ^ swzR)))

    f32x4 acc[8][4];
#pragma unroll
    for (int i = 0; i < 8; ++i)
#pragma unroll
        for (int j = 0; j < 4; ++j) acc[i][j] = (f32x4){0.f, 0.f, 0.f, 0.f};

    // prologue: A(0), B(0), then B(1); allow B(1) to stay in flight
    ISSUE_A(0, 0, 0); ISSUE_A(0, 0, 1); ISSUE_A(0, 0, 2); ISSUE_A(0, 0, 3);
    ISSUE_B(0, 0, 0); ISSUE_B(0, 0, 1); ISSUE_B(0, 0, 2); ISSUE_B(0, 0, 3);
    ISSUE_B(1, 1, 0); ISSUE_B(1, 1, 1); ISSUE_B(1, 1, 2); ISSUE_B(1, 1, 3);
    asm volatile("s_waitcnt vmcnt(4)" ::: "memory");
    __builtin_amdgcn_s_barrier();

    const u16* aF = &As[0][0][0] + (wM * 128 + lm) * 64;
    const u16* bF = &Bs[0][0][0] + (wN * 64 + lm) * 64;

#pragma unroll 1
    for (int t = 0; t < NT; ++t) {
        const int slot = t & 1;
        const u16* aT = aF + slot * 16384;
        const u16* bT = bF + slot * 16384;
        bf16x8 b0[4], b1[4], af[8];

        // ---- phase 0: stage A(t+1) (all 4 quarters); read all B + A-k0; MFMA k0 ----
        if (t + 1 < NT) {
            ISSUE_A(slot ^ 1, t + 1, 0); ISSUE_A(slot ^ 1, t + 1, 1);
            ISSUE_A(slot ^ 1, t + 1, 2); ISSUE_A(slot ^ 1, t + 1, 3);
        }
        b0[0] = LDBH(0, 0); b0[1] = LDBH(1, 0); b0[2] = LDBH(2, 0); b0[3] = LDBH(3, 0);
#pragma unroll
        for (int m = 0; m < 8; ++m) af[m] = LDAH(m, 0);
        b1[0] = LDBH(0, 1); b1[1] = LDBH(1, 1); b1[2] = LDBH(2, 1); b1[3] = LDBH(3, 1);
        __builtin_amdgcn_s_barrier();
        __builtin_amdgcn_s_setprio(1);
#pragma unroll
        for (int m = 0; m < 8; ++m)
#pragma unroll
            for (int j = 0; j < 4; ++j)
                acc[m][j] = __builtin_amdgcn_mfma_f32_16x16x32_bf16(af[m], b0[j], acc[m][j], 0, 0, 0);
        __builtin_amdgcn_s_setprio(0);
        __builtin_amdgcn_s_barrier();

        // ---- phase 1: stage B(t+2) (all 4 quarters); read A-k1; MFMA k1 ----
        if (t + 2 < NT) {
            ISSUE_B(slot, t + 2, 0); ISSUE_B(slot, t + 2, 1);
            ISSUE_B(slot, t + 2, 2); ISSUE_B(slot, t + 2, 3);
        }
#pragma unroll
        for (int m = 0; m < 8; ++m) af[m] = LDAH(m, 1);
        __builtin_amdgcn_s_barrier();
        __builtin_amdgcn_s_setprio(1);
#pragma unroll
        for (int m = 0; m < 8; ++m)
#pragma unroll
            for (int j = 0; j < 4; ++j)
                acc[m][j] = __builtin_amdgcn_mfma_f32_16x16x32_bf16(af[m], b1[j], acc[m][j], 0, 0, 0);
        __builtin_amdgcn_s_setprio(0);
        if (t < NT - 2) {
            asm volatile("s_waitcnt vmcnt(4)" ::: "memory");   // keep B(t+2) in flight
            __builtin_amdgcn_s_barrier();
        } else if (t == NT - 2) {
            asm volatile("s_waitcnt vmcnt(0)" ::: "memory");   // drain last A+B
            __builtin_amdgcn_s_barrier();
        }
    }

    // epilogue: C/D layout col=lane&15, row=(lane>>4)*4+r (verified round 1)
    float* cW = C + (size_t)(m0 + wM * 128 + ((lane >> 4) << 2)) * 2048 + (n0 + wN * 64 + lm);
#pragma unroll
    for (int i = 0; i < 8; ++i)
#pragma unroll
        for (int j = 0; j < 4; ++j) {
            f32x4 v = acc[i][j];
#pragma unroll
            for (int r = 0; r < 4; ++r)
                cW[(size_t)(i * 16 + r) * 2048 + j * 16] = v[r];
        }
}

extern "C" void kernel_launch(void* const* d_in, const int* in_sizes, int n_in,
                              void* d_out, int out_size, void* d_ws, size_t ws_size,
                              hipStream_t stream) {
    const float* x  = (const float*)d_in[0];
    const float* f0 = (const float*)d_in[1];
    const float* f1 = (const float*)d_in[2];
    const float* f2 = (const float*)d_in[3];
    const float* f3 = (const float*)d_in[4];
    float* out = (float*)d_out;

    char* ws = (char*)d_ws;
    u16*   Wt  = (u16*)ws;                       // 8 MB  : W^T bf16 [2048][2048]
    float* H12 = (float*)(ws + (8u << 20));      // 1 MB  : [4096][64]
    float* H34 = (float*)(ws + (9u << 20));      // 256 KB: [64][1024]
    u16*   xb  = (u16*)(ws + (10u << 20));       // 32 MB : x in bf16
    if (ws_size < ((size_t)42 << 20)) return;

    h12_kernel<<<1024, 256, 0, stream>>>(f0, f1, H12);
    h34_kernel<<<256, 256, 0, stream>>>(f2, f3, H34);
    wgen_kernel<<<dim3(16, 64), 256, 0, stream>>>(H12, H34, Wt);
    xcast_kernel<<<8192, 256, 0, stream>>>(x, xb);
    gemm_kernel<<<256, 512, 0, stream>>>(xb, Wt, out);
}

// Round 5
// 67.481 us; speedup vs baseline: 2.1357x; 1.7369x over previous
//
#include <hip/hip_runtime.h>
#include <hip/hip_bf16.h>
#include <stdint.h>

typedef unsigned short u16;
typedef __attribute__((ext_vector_type(4))) unsigned short u16x4;
typedef __attribute__((ext_vector_type(8))) unsigned short u16x8;
typedef __attribute__((ext_vector_type(8))) __bf16 bf16x8;
typedef __attribute__((ext_vector_type(4))) float f32x4;

__device__ __forceinline__ u16 f2bf(float f) {
    uint32_t u = __builtin_bit_cast(uint32_t, f);
    u = (u + 0x7fffu + ((u >> 16) & 1u)) >> 16;
    return (u16)u;
}

__device__ __forceinline__ bf16x8 cvt8(const float* p) {
    f32x4 a = *(const f32x4*)p;
    f32x4 b = *(const f32x4*)(p + 4);
    u16x8 o;
    o[0] = f2bf(a[0]); o[1] = f2bf(a[1]); o[2] = f2bf(a[2]); o[3] = f2bf(a[3]);
    o[4] = f2bf(b[0]); o[5] = f2bf(b[1]); o[6] = f2bf(b[2]); o[7] = f2bf(b[3]);
    return __builtin_bit_cast(bf16x8, o);
}

// ---------------- H12flat[(i1*64+i2)*64 + a*8+b] = (G1[:,i1,:] @ G2[:,i2,:])[a][b]
__global__ __launch_bounds__(256) void h12_kernel(const float* __restrict__ f0,
                                                  const float* __restrict__ f1,
                                                  float* __restrict__ H12) {
    int gid = blockIdx.x * 256 + threadIdx.x;       // 262144
    int slice = gid >> 6;
    int e = gid & 63;
    int a = e >> 3, b = e & 7;
    int i1 = slice >> 6, i2 = slice & 63;
    float s = 0.f;
#pragma unroll
    for (int m = 0; m < 8; m++)
        s += f0[a * 512 + i1 * 8 + m] * f1[m * 512 + i2 * 8 + b];
    H12[gid] = s;
}

// ---------------- H34T[c][e] = (M3M4)[b][a] for e=a*8+b, c=i3*16+i4   (bf16, [1024][64])
__global__ __launch_bounds__(256) void h34t_kernel(const float* __restrict__ f2,
                                                   const float* __restrict__ f3,
                                                   u16* __restrict__ H34T) {
    int gid = blockIdx.x * 256 + threadIdx.x;       // 65536
    int c = gid >> 6;
    int e = gid & 63;
    int a = e >> 3, b = e & 7;                      // value = (M3M4)[b][a]
    int i3 = c >> 4, i4 = c & 15;
    float s = 0.f;
#pragma unroll
    for (int cc = 0; cc < 8; cc++)
        s += f2[b * 512 + i3 * 8 + cc] * f3[cc * 128 + i4 * 8 + a];
    H34T[c * 64 + e] = f2bf(s);
}

// ---------------- H12bT[p*64+e][k] = bf16(H12flat[(i1*64 + 2*j2 + p)*64 + e]), k=i1*32+j2
__global__ __launch_bounds__(256) void h12t_kernel(const float* __restrict__ H12,
                                                   u16* __restrict__ H12bT) {
    int idx = blockIdx.x * 256 + threadIdx.x;       // 262144 ([128][2048])
    int rc = idx >> 11;                              // p*64+e
    int k = idx & 2047;
    int p = rc >> 6, e = rc & 63;
    int i1 = k >> 5, j2 = k & 31;
    H12bT[idx] = f2bf(H12[((i1 << 6) + (j2 << 1) + p) * 64 + e]);
}

// ---------------- K1: Yp[ks] += x(rows,kseg) @ H12bT^T ; split-K=8, f32 partials
// grid (64, 8), block 256 = 4 waves x 32 rows; per block K-range = 256 (8 chunks of 32)
__global__ __launch_bounds__(256) void k1_kernel(const float* __restrict__ x,
                                                 const u16* __restrict__ H12bT,
                                                 float* __restrict__ Yp) {
    int tid = threadIdx.x, lane = tid & 63, w = tid >> 6;
    int lm = lane & 15, lkE = (lane >> 4) << 3;
    int r0 = blockIdx.x * 128 + w * 32;
    int k0 = blockIdx.y * 256;

    f32x4 acc[2][8];
#pragma unroll
    for (int i = 0; i < 2; ++i)
#pragma unroll
        for (int j = 0; j < 8; ++j) acc[i][j] = (f32x4){0.f, 0.f, 0.f, 0.f};

    const float* xA0 = x + (size_t)(r0 + lm) * 2048 + k0 + lkE;
    const float* xA1 = x + (size_t)(r0 + 16 + lm) * 2048 + k0 + lkE;
    const u16*  bP  = H12bT + (size_t)lm * 2048 + k0 + lkE;

#pragma unroll
    for (int kc = 0; kc < 8; ++kc) {
        int ko = kc * 32;
        bf16x8 a0 = cvt8(xA0 + ko);
        bf16x8 a1 = cvt8(xA1 + ko);
        bf16x8 bf[8];
#pragma unroll
        for (int j = 0; j < 8; ++j)
            bf[j] = __builtin_bit_cast(bf16x8, *(const u16x8*)(bP + (size_t)j * 16 * 2048 + ko));
#pragma unroll
        for (int j = 0; j < 8; ++j) {
            acc[0][j] = __builtin_amdgcn_mfma_f32_16x16x32_bf16(a0, bf[j], acc[0][j], 0, 0, 0);
            acc[1][j] = __builtin_amdgcn_mfma_f32_16x16x32_bf16(a1, bf[j], acc[1][j], 0, 0, 0);
        }
    }
    // Yp[ks][row][col] f32 ; row = r0 + mi*16 + (lane>>4)*4 + r ; col = j*16 + lm
    float* yw = Yp + ((size_t)blockIdx.y * 8192 + r0 + ((lane >> 4) << 2)) * 128 + lm;
#pragma unroll
    for (int mi = 0; mi < 2; ++mi)
#pragma unroll
        for (int j = 0; j < 8; ++j) {
            f32x4 v = acc[mi][j];
#pragma unroll
            for (int r = 0; r < 4; ++r)
                yw[(size_t)(mi * 16 + r) * 128 + j * 16] = v[r];
        }
}

// ---------------- reduce 8 partials -> Yb bf16 [8192][128]
__global__ __launch_bounds__(256) void yred_kernel(const float* __restrict__ Yp,
                                                   u16* __restrict__ Yb) {
    int i = (blockIdx.x * 256 + threadIdx.x) * 4;   // 1M elems, grid 1024
    f32x4 s = (f32x4){0.f, 0.f, 0.f, 0.f};
#pragma unroll
    for (int ks = 0; ks < 8; ++ks)
        s += *(const f32x4*)(Yp + (size_t)ks * 1048576 + i);
    u16x4 o;
    o[0] = f2bf(s[0]); o[1] = f2bf(s[1]); o[2] = f2bf(s[2]); o[3] = f2bf(s[3]);
    *(u16x4*)(Yb + i) = o;
}

// ---------------- K2: out = Yb(:, half p) @ H34T^T ; K=64, LDS-free
// grid (16, 64), block 256 = 4 waves x 32 rows; tile 128 rows x 128 cols
__global__ __launch_bounds__(256) void k2_kernel(const u16* __restrict__ Yb,
                                                 const u16* __restrict__ H34T,
                                                 float* __restrict__ out) {
    int tid = threadIdx.x, lane = tid & 63, w = tid >> 6;
    int lm = lane & 15, lkE = (lane >> 4) << 3;
    int n0 = blockIdx.x * 128;
    int p = n0 >> 10;
    int c0 = n0 & 1023;
    int r0 = blockIdx.y * 128 + w * 32;

    f32x4 acc[2][8];
#pragma unroll
    for (int i = 0; i < 2; ++i)
#pragma unroll
        for (int j = 0; j < 8; ++j) acc[i][j] = (f32x4){0.f, 0.f, 0.f, 0.f};

    const u16* aB = Yb + (size_t)(r0 + lm) * 128 + p * 64 + lkE;
    const u16* bB = H34T + (size_t)(c0 + lm) * 64 + lkE;

#pragma unroll
    for (int kk = 0; kk < 2; ++kk) {
        int ko = kk * 32;
        bf16x8 a0 = __builtin_bit_cast(bf16x8, *(const u16x8*)(aB + ko));
        bf16x8 a1 = __builtin_bit_cast(bf16x8, *(const u16x8*)(aB + 16 * 128 + ko));
        bf16x8 bf[8];
#pragma unroll
        for (int j = 0; j < 8; ++j)
            bf[j] = __builtin_bit_cast(bf16x8, *(const u16x8*)(bB + (size_t)j * 16 * 64 + ko));
#pragma unroll
        for (int j = 0; j < 8; ++j) {
            acc[0][j] = __builtin_amdgcn_mfma_f32_16x16x32_bf16(a0, bf[j], acc[0][j], 0, 0, 0);
            acc[1][j] = __builtin_amdgcn_mfma_f32_16x16x32_bf16(a1, bf[j], acc[1][j], 0, 0, 0);
        }
    }
    float* cW = out + (size_t)(r0 + ((lane >> 4) << 2)) * 2048 + n0 + lm;
#pragma unroll
    for (int mi = 0; mi < 2; ++mi)
#pragma unroll
        for (int j = 0; j < 8; ++j) {
            f32x4 v = acc[mi][j];
#pragma unroll
            for (int r = 0; r < 4; ++r)
                cW[(size_t)(mi * 16 + r) * 2048 + j * 16] = v[r];
        }
}

extern "C" void kernel_launch(void* const* d_in, const int* in_sizes, int n_in,
                              void* d_out, int out_size, void* d_ws, size_t ws_size,
                              hipStream_t stream) {
    const float* x  = (const float*)d_in[0];
    const float* f0 = (const float*)d_in[1];
    const float* f1 = (const float*)d_in[2];
    const float* f2 = (const float*)d_in[3];
    const float* f3 = (const float*)d_in[4];
    float* out = (float*)d_out;

    char* ws = (char*)d_ws;
    float* H12f  = (float*)ws;                          // 1 MB   [4096][64] f32
    u16*   H12bT = (u16*)(ws + (1u << 20));             // 512 KB [128][2048] bf16
    u16*   H34T  = (u16*)(ws + ((1u << 20) + (512u << 10)));  // 128 KB [1024][64] bf16
    float* Yp    = (float*)(ws + (2u << 20));           // 32 MB  [8][8192][128] f32
    u16*   Yb    = (u16*)(ws + (34u << 20));            // 2 MB   [8192][128] bf16
    if (ws_size < ((size_t)38 << 20)) return;

    h12_kernel<<<1024, 256, 0, stream>>>(f0, f1, H12f);
    h34t_kernel<<<256, 256, 0, stream>>>(f2, f3, H34T);
    h12t_kernel<<<1024, 256, 0, stream>>>(H12f, H12bT);
    k1_kernel<<<dim3(64, 8), 256, 0, stream>>>(x, H12bT, Yp);
    yred_kernel<<<1024, 256, 0, stream>>>(Yp, Yb);
    k2_kernel<<<dim3(16, 64), 256, 0, stream>>>(Yb, H34T, out);
}